// Round 11
// baseline (1354.621 us; speedup 1.0000x reference)
//
#include <hip/hip_runtime.h>
#include <stdint.h>

#define T_STEPS 800
#define NBATCH  32
#define SST     1024
#define ROW     5120   // SST * 5 floats per (t, n) row
#define RING    5      // LDS ring depth

// 16B-block swizzle (involution): spreads stride-5-block access across banks.
__device__ __forceinline__ int swz(int p) { return p ^ ((p >> 3) & 7); }

__device__ __forceinline__ float lse5(float v0, float v1, float v2, float v3, float v4) {
  float m = fmaxf(fmaxf(fmaxf(v0, v1), fmaxf(v2, v3)), v4);
  float s = __expf(v0 - m) + __expf(v1 - m) + __expf(v2 - m) +
            __expf(v3 - m) + __expf(v4 - m);
  return m + __logf(s);
}

#define WAITVM(N) do { \
  asm volatile("s_waitcnt vmcnt(" #N ")" ::: "memory"); \
  __builtin_amdgcn_sched_barrier(0); } while (0)

// Block barrier draining LDS ops only; DMA (vmcnt) stays in flight.
__device__ __forceinline__ void barrier_lgkm() {
  asm volatile("s_waitcnt lgkmcnt(0)" ::: "memory");
  __builtin_amdgcn_s_barrier();
  asm volatile("" ::: "memory");
}

// Async DMA global->LDS, 16B/lane. Global src is PER-LANE (pre-swizzled);
// LDS dst = uniform base + lane*16 (linear).
__device__ __forceinline__ void stage16(const float* g, float* l) {
  __builtin_amdgcn_global_load_lds(
      (const __attribute__((address_space(1))) uint32_t*)g,
      (__attribute__((address_space(3))) uint32_t*)l, 16, 0, 0);
}

// Roles within a 1024-thread block (16 waves):
//   waves 0..3   : compute (256 threads, R7 state maps; NO counted vmcnt)
//   waves 4..13  : staging (2 stage16/step each; own vmcnt stream, WAITVM(6))
//   waves 14..15 : idle (barrier keep-alive)
// fwd compute waves also write out0 straight from registers.
template <int DIR>
__device__ void scan_run(const float* __restrict__ scores, float* __restrict__ out,
                         float* __restrict__ out0, int n,
                         float (*ring)[ROW], float (*abuf)[SST]) {
  const int tid  = threadIdx.x;
  const int wv   = tid >> 6;
  const int lane = tid & 63;
  const float* base = scores + (size_t)n * ROW;
  float* outn = out + (size_t)n * (T_STEPS + 1) * SST;

  if (wv < 4) {
    // -------------------- compute waves --------------------
    const int u = tid;  // 0..255
    float a[4] = {0.f, 0.f, 0.f, 0.f};
    float* o0n = out0 + (size_t)n * T_STEPS * ROW;

    // Precomputed swizzled LDS offsets (dwords).
    int fvo[5];                              // 5 float4 reads: blocks 5u+m
#pragma unroll
    for (int m = 0; m < 5; ++m) fvo[m] = swz(5 * u + m) << 2;
    const int gbo = swz(u) << 2;             // block u: fwd publish / bwd gather
    int pvo[4];                              // state u+256k (fwd gather / bwd publish)
#pragma unroll
    for (int k = 0; k < 4; ++k) pvo[k] = (swz((u >> 2) + 64 * k) << 2) | (u & 3);
    int svo[4];                              // bwd self scores: float 5u+1280j
#pragma unroll
    for (int j = 0; j < 4; ++j) {
      const int f = 5 * u + 1280 * j;
      svo[j] = (swz(f >> 2) << 2) | (f & 3);
    }

    // init alpha[0]=0 / beta[T]=0 (before first barrier)
    {
      const float4 z = {0.f, 0.f, 0.f, 0.f};
      *(float4*)(&abuf[0][0] + gbo) = z;
      const size_t t0 = DIR ? (size_t)T_STEPS : 0;
      ((float4*)(outn + t0 * SST))[u] = z;
    }

    int cs = 0;
    for (int s = 0; s < T_STEPS; ++s) {
      barrier_lgkm();  // joins staging certs; publishes abuf of step s-1
      const float* rb = ring[cs];
      const int cur = s & 1, nxt = cur ^ 1;

      float4 q0 = *(const float4*)(rb + fvo[0]);
      float4 q1 = *(const float4*)(rb + fvo[1]);
      float4 q2 = *(const float4*)(rb + fvo[2]);
      float4 q3 = *(const float4*)(rb + fvo[3]);
      float4 q4 = *(const float4*)(rb + fvo[4]);
      float fv[20];
      fv[0]=q0.x; fv[1]=q0.y; fv[2]=q0.z; fv[3]=q0.w;
      fv[4]=q1.x; fv[5]=q1.y; fv[6]=q1.z; fv[7]=q1.w;
      fv[8]=q2.x; fv[9]=q2.y; fv[10]=q2.z; fv[11]=q2.w;
      fv[12]=q3.x; fv[13]=q3.y; fv[14]=q3.z; fv[15]=q3.w;
      fv[16]=q4.x; fv[17]=q4.y; fv[18]=q4.z; fv[19]=q4.w;

      float na[4];
      if constexpr (!DIR) {
        const float p0 = abuf[cur][pvo[0]];
        const float p1 = abuf[cur][pvo[1]];
        const float p2 = abuf[cur][pvo[2]];
        const float p3 = abuf[cur][pvo[3]];
#pragma unroll
        for (int j = 0; j < 4; ++j) {
          na[j] = lse5(fv[5*j] + a[j], fv[5*j+1] + p0, fv[5*j+2] + p1,
                       fv[5*j+3] + p2, fv[5*j+4] + p3);
          a[j] = na[j];
        }
        const float4 o = {na[0], na[1], na[2], na[3]};
        ((float4*)(outn + (size_t)(s + 1) * SST))[u] = o;   // scan row
        *(float4*)(&abuf[nxt][0] + gbo) = o;                // publish
        // fused out0 from registers (row t=s), full coverage across threads
        float* od = o0n + (size_t)s * ROW + 20 * u;
        *(float4*)(od +  0) = q0; *(float4*)(od +  4) = q1;
        *(float4*)(od +  8) = q2; *(float4*)(od + 12) = q3;
        *(float4*)(od + 16) = q4;
      } else {
        const float4 pv = *(const float4*)(&abuf[cur][0] + gbo);  // beta[4u..4u+3]
        const int t = T_STEPS - 1 - s;
#pragma unroll
        for (int j = 0; j < 4; ++j) {
          na[j] = lse5(rb[svo[j]] + a[j], fv[1+j] + pv.x, fv[6+j] + pv.y,
                       fv[11+j] + pv.z, fv[16+j] + pv.w);
          a[j] = na[j];
          outn[(size_t)t * SST + u + 256 * j] = na[j];
          abuf[nxt][pvo[j]] = na[j];
        }
      }
      cs = (cs + 1 == RING) ? 0 : cs + 1;
    }
  } else if (wv < 14) {
    // -------------------- staging waves --------------------
    const int sw = wv - 4;            // 0..9, stages blocks [128*sw, 128*sw+128)
    const int B0 = 128 * sw;
    int so0 = swz(B0 + lane) << 2;         // per-lane pre-swizzled src (floats)
    int so1 = swz(B0 + 64 + lane) << 2;
    const int d0 = B0 << 2, d1 = (B0 + 64) << 2;  // linear LDS dst (floats)

    // prologue: rows 0..3 (8 ops; uniform WAITVM(6) afterwards)
#pragma unroll
    for (int i = 0; i < 4; ++i) {
      const int t = DIR ? (T_STEPS - 1 - i) : i;
      const float* rowg = base + (size_t)t * (NBATCH * ROW);
      stage16(rowg + so0, &ring[i][0] + d0);
      stage16(rowg + so1, &ring[i][0] + d1);
    }
    int ss = 4;  // at step s, stage row s+4 into slot (s+4)%5
    for (int s = 0; s < T_STEPS; ++s) {
      if (s < 797) WAITVM(6); else WAITVM(0);
      barrier_lgkm();
      if (s + 4 < T_STEPS) {
        const int tr = DIR ? (T_STEPS - 1 - (s + 4)) : (s + 4);
        const float* rowg = base + (size_t)tr * (NBATCH * ROW);
        stage16(rowg + so0, &ring[ss][0] + d0);
        stage16(rowg + so1, &ring[ss][0] + d1);
      }
      ss = (ss + 1 == RING) ? 0 : ss + 1;
    }
  } else {
    // -------------------- idle waves (barrier keep-alive) --------------------
    for (int s = 0; s < T_STEPS; ++s) barrier_lgkm();
  }
}

__global__ __launch_bounds__(1024, 1) void mega(const float* __restrict__ scores,
                                                float* __restrict__ out0,
                                                float* __restrict__ bwdo,
                                                float* __restrict__ fposts) {
  __shared__ float ring[RING][ROW];   // 100 KB score ring (swizzled layout)
  __shared__ float abuf[2][SST];      // 8 KB alpha/beta exchange (swizzled)
  const int b = blockIdx.x;
  if (b < NBATCH) scan_run<0>(scores, fposts, out0, b, ring, abuf);
  else            scan_run<1>(scores, bwdo,   out0, b - NBATCH, ring, abuf);
}

// One wave per row of 1024: posts = softmax(fwd + bwd), in place over fwd buffer.
__global__ __launch_bounds__(256) void posts_kernel(float* __restrict__ fp,
                                                    const float* __restrict__ bp) {
  const int lane = threadIdx.x & 63;
  const int wid  = threadIdx.x >> 6;
  const size_t row = (size_t)blockIdx.x * 4 + wid;
  float* f = fp + row * SST;
  const float* b = bp + row * SST;

  float x[16];
#pragma unroll
  for (int k = 0; k < 4; ++k) {
    const float4 fv = ((const float4*)f)[lane + 64 * k];
    const float4 bv = ((const float4*)b)[lane + 64 * k];
    x[4 * k + 0] = fv.x + bv.x;
    x[4 * k + 1] = fv.y + bv.y;
    x[4 * k + 2] = fv.z + bv.z;
    x[4 * k + 3] = fv.w + bv.w;
  }
  float m = x[0];
#pragma unroll
  for (int j = 1; j < 16; ++j) m = fmaxf(m, x[j]);
#pragma unroll
  for (int off = 32; off >= 1; off >>= 1) m = fmaxf(m, __shfl_xor(m, off));
  float ssum = 0.0f;
#pragma unroll
  for (int j = 0; j < 16; ++j) { x[j] = __expf(x[j] - m); ssum += x[j]; }
#pragma unroll
  for (int off = 32; off >= 1; off >>= 1) ssum += __shfl_xor(ssum, off);
  const float inv = 1.0f / ssum;
#pragma unroll
  for (int k = 0; k < 4; ++k) {
    float4 o;
    o.x = x[4 * k + 0] * inv;
    o.y = x[4 * k + 1] * inv;
    o.z = x[4 * k + 2] * inv;
    o.w = x[4 * k + 3] * inv;
    ((float4*)f)[lane + 64 * k] = o;
  }
}

extern "C" void kernel_launch(void* const* d_in, const int* in_sizes, int n_in,
                              void* d_out, int out_size, void* d_ws, size_t ws_size,
                              hipStream_t stream) {
  (void)in_sizes; (void)n_in; (void)d_ws; (void)ws_size; (void)out_size;
  const float* scores = (const float*)d_in[0];
  float* out = (float*)d_out;
  float* out0   = out;                                                  // (32,800,5120)
  float* bwdo   = out + (size_t)NBATCH * T_STEPS * ROW;                 // (32,801,1024)
  float* fposts = bwdo + (size_t)NBATCH * (T_STEPS + 1) * SST;          // (32,801,1024)

  mega<<<2 * NBATCH, 1024, 0, stream>>>(scores, out0, bwdo, fposts);
  posts_kernel<<<(NBATCH * (T_STEPS + 1)) / 4, 256, 0, stream>>>(fposts, bwdo);
}